// Round 2
// baseline (2933.767 us; speedup 1.0000x reference)
//
#include <hip/hip_runtime.h>
#include <math.h>

#define BATCH    2
#define SEQ      4096
#define DMODEL   2048
#define DSTATE   64
#define HEADDIM  128
#define NHEADS   32
#define DINNER   4096
#define CONVDIM  4224
#define DINPROJ  8352
#define NCHUNK   16
#define CHUNKL   256
#define ROWS     (BATCH*SEQ)   // 8192

typedef __attribute__((ext_vector_type(8))) __bf16 bf16x8;
typedef __attribute__((ext_vector_type(4))) float floatx4;

__device__ __forceinline__ unsigned short f2bf(float f) {
    union { float f; unsigned int u; } v; v.f = f;
    unsigned int u = v.u;
    unsigned int r = (u + 0x7FFFu + ((u >> 16) & 1u)) >> 16;
    return (unsigned short)r;
}
__device__ __forceinline__ float bf2f(unsigned short s) {
    union { unsigned int u; float f; } v; v.u = ((unsigned int)s) << 16;
    return v.f;
}

// ---------------- GEMM: C[M,N] = A[M,K] * Bt[N,K]^T + bias[N] ----------------
// bf16 MFMA 16x16x32, 128x128 block tile, 4 waves (2x2), each wave 64x64 (4x4 tiles)
// A_BF16: A is bf16 (else fp32, converted during staging). OUT_BF16: C stored bf16.
template<int A_BF16, int OUT_BF16>
__global__ __launch_bounds__(256) void gemm_bt(
    const void* __restrict__ Ap, int lda,
    const float* __restrict__ Bt, int ldb,
    const float* __restrict__ bias,
    void* __restrict__ Cp, int ldc,
    int M, int N, int K)
{
    __shared__ __align__(16) unsigned short As[128][32];
    __shared__ __align__(16) unsigned short Bs[128][32];
    const int tid  = threadIdx.x;
    const int bm   = blockIdx.x;
    const int bn   = blockIdx.y;
    const int wave = tid >> 6;
    const int lane = tid & 63;
    const int wm   = (wave >> 1) * 64;
    const int wn   = (wave & 1) * 64;
    const int q    = lane >> 4;
    const int lm   = lane & 15;

    floatx4 acc[4][4] = {};

    const int arow0 = bm * 128;
    const int brow0 = bn * 128;

    for (int k0 = 0; k0 < K; k0 += 32) {
        __syncthreads();
        #pragma unroll
        for (int i = 0; i < 4; ++i) {
            int idx = tid + 256 * i;          // 0..1023
            int r   = idx >> 3;               // 0..127
            int kq  = (idx & 7) * 4;          // 0..28
            if (A_BF16) {
                ushort4 pa = *reinterpret_cast<const ushort4*>(
                    (const unsigned short*)Ap + (size_t)(arow0 + r) * lda + k0 + kq);
                *reinterpret_cast<ushort4*>(&As[r][kq]) = pa;
            } else {
                float4 va = *reinterpret_cast<const float4*>(
                    (const float*)Ap + (size_t)(arow0 + r) * lda + k0 + kq);
                ushort4 pa;
                pa.x = f2bf(va.x); pa.y = f2bf(va.y); pa.z = f2bf(va.z); pa.w = f2bf(va.w);
                *reinterpret_cast<ushort4*>(&As[r][kq]) = pa;
            }
            int br = brow0 + r;
            float4 vb;
            if (br < N) vb = *reinterpret_cast<const float4*>(&Bt[(size_t)br * ldb + k0 + kq]);
            else        vb = make_float4(0.f, 0.f, 0.f, 0.f);
            ushort4 pb;
            pb.x = f2bf(vb.x); pb.y = f2bf(vb.y); pb.z = f2bf(vb.z); pb.w = f2bf(vb.w);
            *reinterpret_cast<ushort4*>(&Bs[r][kq]) = pb;
        }
        __syncthreads();
        bf16x8 af[4], bfv[4];
        #pragma unroll
        for (int mt = 0; mt < 4; ++mt)
            af[mt] = *reinterpret_cast<const bf16x8*>(&As[wm + mt * 16 + lm][q * 8]);
        #pragma unroll
        for (int nt = 0; nt < 4; ++nt)
            bfv[nt] = *reinterpret_cast<const bf16x8*>(&Bs[wn + nt * 16 + lm][q * 8]);
        #pragma unroll
        for (int mt = 0; mt < 4; ++mt)
            #pragma unroll
            for (int nt = 0; nt < 4; ++nt)
                acc[mt][nt] = __builtin_amdgcn_mfma_f32_16x16x32_bf16(af[mt], bfv[nt], acc[mt][nt], 0, 0, 0);
    }

    #pragma unroll
    for (int mt = 0; mt < 4; ++mt) {
        #pragma unroll
        for (int nt = 0; nt < 4; ++nt) {
            int col = brow0 + wn + nt * 16 + lm;
            if (col < N) {
                float bv = bias[col];
                #pragma unroll
                for (int r = 0; r < 4; ++r) {
                    int row = arow0 + wm + mt * 16 + q * 4 + r;
                    float v = acc[mt][nt][r] + bv;
                    if (OUT_BF16)
                        ((unsigned short*)Cp)[(size_t)row * ldc + col] = f2bf(v);
                    else
                        ((float*)Cp)[(size_t)row * ldc + col] = v;
                }
            }
        }
    }
}

// ---------------- causal depthwise conv (w=4) + bias + SiLU ----------------
__global__ __launch_bounds__(256) void conv_silu(
    const unsigned short* __restrict__ zx, const float* __restrict__ conv_w,
    const float* __restrict__ conv_b, unsigned short* __restrict__ xBC)
{
    int idx = blockIdx.x * 256 + threadIdx.x;      // over ROWS*CONVDIM
    int ch  = idx % CONVDIM;
    int l   = (idx / CONVDIM) % SEQ;
    int b   = idx / (CONVDIM * SEQ);
    const unsigned short* base = zx + (size_t)(b * SEQ) * DINPROJ + DINNER + ch;
    float s = conv_b[ch];
    #pragma unroll
    for (int j = 0; j < 4; ++j) {
        int lj = l - 3 + j;
        if (lj >= 0) s += conv_w[ch * 4 + j] * bf2f(base[(size_t)lj * DINPROJ]);
    }
    float sig = 1.f / (1.f + expf(-s));
    xBC[idx] = f2bf(s * sig);
}

// -------- fused: dt=softplus(raw+bias), adt=-exp(A_log)*dt, per-chunk cumsum --------
__global__ __launch_bounds__(256) void dtcum_kernel(
    const unsigned short* __restrict__ zx, const float* __restrict__ dt_bias,
    const float* __restrict__ A_log, float* __restrict__ dtb,
    float* __restrict__ cum, float* __restrict__ csum)
{
    int id = blockIdx.x;                 // (b*16+c)*32+h
    int h  = id & 31;
    int c  = (id >> 5) & 15;
    int b  = id >> 9;
    int t  = threadIdx.x;
    int row = b * SEQ + c * CHUNKL + t;
    float v = bf2f(zx[(size_t)row * DINPROJ + DINNER + CONVDIM + h]) + dt_bias[h];
    float dtv = (v > 20.f) ? v : log1pf(expf(v));
    dtb[row * NHEADS + h] = dtv;
    float adt = -expf(A_log[h]) * dtv;
    __shared__ float s[256];
    s[t] = adt;
    __syncthreads();
    for (int off = 1; off < 256; off <<= 1) {
        float x = (t >= off) ? s[t - off] : 0.f;
        __syncthreads();
        s[t] += x;
        __syncthreads();
    }
    cum[id * 256 + t] = s[t];
    if (t == 255) csum[id] = s[255];
}

// ---------------- chunk states: st[p,n] = sum_l B[l,n]*exp(cumlast-cum[l])*Xd[l,p] ----------------
__global__ __launch_bounds__(256) void states_kernel(
    const unsigned short* __restrict__ xBC, const float* __restrict__ dtb,
    const float* __restrict__ cum, float* __restrict__ states)
{
    int id = blockIdx.x;                 // (b*16+c)*32+h
    int h  = id & 31;
    int c  = (id >> 5) & 15;
    int b  = id >> 9;
    int t  = threadIdx.x;
    int p  = t >> 1;
    int nh = (t & 1) * 32;
    __shared__ float Btile[32][64];
    __shared__ float Xdt[32][128];
    __shared__ float wl[32];
    float st[32] = {};
    int cumbase = id * 256;
    float cumlast = cum[cumbase + 255];
    for (int lt = 0; lt < 256; lt += 32) {
        __syncthreads();
        #pragma unroll
        for (int i = 0; i < 8; ++i) {
            int idx2 = t + i * 256;          // 2048 = 32*64
            int s2 = idx2 >> 6, n2 = idx2 & 63;
            int row = b * SEQ + c * CHUNKL + lt + s2;
            Btile[s2][n2] = bf2f(xBC[(size_t)row * CONVDIM + DINNER + n2]);
        }
        #pragma unroll
        for (int i = 0; i < 16; ++i) {
            int idx2 = t + i * 256;          // 4096 = 32*128
            int s2 = idx2 >> 7, p2 = idx2 & 127;
            int row = b * SEQ + c * CHUNKL + lt + s2;
            Xdt[s2][p2] = bf2f(xBC[(size_t)row * CONVDIM + h * HEADDIM + p2]) * dtb[row * NHEADS + h];
        }
        if (t < 32) wl[t] = expf(cumlast - cum[cumbase + lt + t]);
        __syncthreads();
        for (int s2 = 0; s2 < 32; ++s2) {
            float f = wl[s2] * Xdt[s2][p];
            #pragma unroll
            for (int n2 = 0; n2 < 32; ++n2) st[n2] += f * Btile[s2][nh + n2];
        }
    }
    size_t obase = (size_t)id * 8192 + (size_t)p * 64 + nh;
    #pragma unroll
    for (int n2 = 0; n2 < 32; ++n2) states[obase + n2] = st[n2];
}

// ---------------- inter-chunk recurrence (in-place: states[c] <- state entering chunk c) ----------------
__global__ __launch_bounds__(256) void inter_kernel(
    float* __restrict__ states, const float* __restrict__ csum)
{
    int idx = blockIdx.x * 256 + threadIdx.x;      // BATCH*NHEADS*8192
    int pn  = idx & 8191;
    int h   = (idx >> 13) & 31;
    int b   = idx >> 18;
    float S = 0.f;
    for (int c = 0; c < 16; ++c) {
        int id = (b * 16 + c) * 32 + h;
        size_t off = (size_t)id * 8192 + pn;
        float st = states[off];
        states[off] = S;
        S = S * expf(csum[id]) + st;
    }
}

// ---------------- Y = Y_diag + Y_off; writes bf16 into zx[:, DINNER + h*128 + ...] ----------------
__global__ __launch_bounds__(256) void y_kernel(
    const unsigned short* __restrict__ xBC, const float* __restrict__ dtb,
    const float* __restrict__ cum, const float* __restrict__ inter,
    unsigned short* __restrict__ zx)
{
    int id = blockIdx.x;                 // (b*16+c)*32+h
    int ph = blockIdx.y;                 // p-half
    int h  = id & 31;
    int c  = (id >> 5) & 15;
    int b  = id >> 9;
    int t  = threadIdx.x;                // = l within chunk
    __shared__ float cums[256];
    __shared__ float interS[64][64];
    __shared__ float Btile[32][64];
    __shared__ float Xdt[32][64];

    int cumbase = id * 256;
    cums[t] = cum[cumbase + t];

    int row_l = b * SEQ + c * CHUNKL + t;
    float creg[64];
    const unsigned short* crow = &xBC[(size_t)row_l * CONVDIM + DINNER + DSTATE];
    #pragma unroll
    for (int n = 0; n < 64; ++n) creg[n] = bf2f(crow[n]);

    size_t ibase = (size_t)id * 8192 + (size_t)ph * 64 * 64;
    #pragma unroll
    for (int i = 0; i < 16; ++i) {
        int idx2 = t + i * 256;          // 4096 = 64*64
        interS[idx2 >> 6][idx2 & 63] = inter[ibase + idx2];
    }
    __syncthreads();

    float mycum = cums[t];
    float efac  = expf(mycum);
    float yacc[64];
    #pragma unroll
    for (int p = 0; p < 64; ++p) yacc[p] = 0.f;

    // Y_off
    for (int n = 0; n < 64; ++n) {
        float cf = creg[n] * efac;
        #pragma unroll
        for (int p = 0; p < 64; ++p) yacc[p] += cf * interS[p][n];
    }

    // Y_diag
    for (int st0 = 0; st0 < 256; st0 += 32) {
        __syncthreads();
        #pragma unroll
        for (int i = 0; i < 8; ++i) {
            int idx2 = t + i * 256;      // 2048 = 32*64
            int s2 = idx2 >> 6, n2 = idx2 & 63;
            int row_s = b * SEQ + c * CHUNKL + st0 + s2;
            Btile[s2][n2] = bf2f(xBC[(size_t)row_s * CONVDIM + DINNER + n2]);
            Xdt[s2][n2]   = bf2f(xBC[(size_t)row_s * CONVDIM + h * HEADDIM + ph * 64 + n2])
                            * dtb[row_s * NHEADS + h];
        }
        __syncthreads();
        if (t >= st0) {
            int lim = t - st0 + 1;
            int smax = (lim < 32) ? lim : 32;
            for (int s2 = 0; s2 < smax; ++s2) {
                float dot = 0.f;
                #pragma unroll
                for (int n = 0; n < 64; ++n) dot += creg[n] * Btile[s2][n];
                float sc = dot * expf(mycum - cums[st0 + s2]);
                #pragma unroll
                for (int p = 0; p < 64; ++p) yacc[p] += sc * Xdt[s2][p];
            }
        }
    }

    size_t ybase = (size_t)row_l * DINPROJ + DINNER + h * HEADDIM + ph * 64;
    #pragma unroll
    for (int p = 0; p < 64; ++p) zx[ybase + p] = f2bf(yacc[p]);
}

// ---------------- y * silu(z), LayerNorm (in place over y region of zx, bf16) ----------------
__global__ __launch_bounds__(256) void gate_ln(
    unsigned short* __restrict__ zx, const float* __restrict__ ln_w, const float* __restrict__ ln_b)
{
    int row = blockIdx.x;
    int t   = threadIdx.x;
    size_t base = (size_t)row * DINPROJ;
    float g[16];
    float sum = 0.f, sumsq = 0.f;
    #pragma unroll
    for (int j = 0; j < 16; ++j) {
        int i = t + j * 256;
        float z = bf2f(zx[base + i]);
        float y = bf2f(zx[base + DINNER + i]);
        float sig = 1.f / (1.f + expf(-z));
        float v = y * z * sig;
        g[j] = v;
        sum += v; sumsq += v * v;
    }
    __shared__ float rs[256], rq[256];
    rs[t] = sum; rq[t] = sumsq;
    __syncthreads();
    for (int off = 128; off > 0; off >>= 1) {
        if (t < off) { rs[t] += rs[t + off]; rq[t] += rq[t + off]; }
        __syncthreads();
    }
    float mu   = rs[0] * (1.f / DINNER);
    float var  = rq[0] * (1.f / DINNER) - mu * mu;
    float rstd = rsqrtf(var + 1e-5f);
    #pragma unroll
    for (int j = 0; j < 16; ++j) {
        int i = t + j * 256;
        zx[base + DINNER + i] = f2bf((g[j] - mu) * rstd * ln_w[i] + ln_b[i]);
    }
}

extern "C" void kernel_launch(void* const* d_in, const int* in_sizes, int n_in,
                              void* d_out, int out_size, void* d_ws, size_t ws_size,
                              hipStream_t stream)
{
    const float* u          = (const float*)d_in[0];
    const float* in_proj_w  = (const float*)d_in[1];
    const float* in_proj_b  = (const float*)d_in[2];
    const float* conv_w     = (const float*)d_in[3];
    const float* conv_b     = (const float*)d_in[4];
    const float* dt_bias    = (const float*)d_in[5];
    const float* A_log      = (const float*)d_in[6];
    const float* ln_w       = (const float*)d_in[7];
    const float* ln_b       = (const float*)d_in[8];
    const float* out_proj_w = (const float*)d_in[9];
    const float* out_proj_b = (const float*)d_in[10];
    float* out = (float*)d_out;

    // workspace layout (bf16 big buffers): total ~230.5 MiB
    unsigned short* zx  = (unsigned short*)d_ws;              // ROWS*DINPROJ bf16
    unsigned short* xBC = zx + (size_t)ROWS * DINPROJ;        // ROWS*CONVDIM bf16
    float* dtb    = (float*)(xBC + (size_t)ROWS * CONVDIM);   // ROWS*NHEADS f32
    float* cum    = dtb + (size_t)ROWS * NHEADS;              // ROWS*NHEADS f32
    float* csum   = cum + (size_t)ROWS * NHEADS;              // 1024 f32
    float* states = csum + 1024;                              // 1024*8192 f32

    dim3 blk(256);

    // 1) in_proj GEMM: zx = u @ in_proj_w^T + b   (fp32 A -> bf16 out)
    gemm_bt<0, 1><<<dim3(ROWS / 128, (DINPROJ + 127) / 128), blk, 0, stream>>>(
        (const void*)u, DMODEL, in_proj_w, DMODEL, in_proj_b, (void*)zx, DINPROJ, ROWS, DINPROJ, DMODEL);

    // 2) conv + silu -> xBC (bf16)
    conv_silu<<<dim3((ROWS * CONVDIM) / 256), blk, 0, stream>>>(zx, conv_w, conv_b, xBC);

    // 3+4) dt / adt / per-chunk cumsum
    dtcum_kernel<<<dim3(BATCH * NCHUNK * NHEADS), blk, 0, stream>>>(zx, dt_bias, A_log, dtb, cum, csum);

    // 5) chunk states
    states_kernel<<<dim3(BATCH * NCHUNK * NHEADS), blk, 0, stream>>>(xBC, dtb, cum, states);

    // 6) inter-chunk recurrence (in place)
    inter_kernel<<<dim3((BATCH * NHEADS * 8192) / 256), blk, 0, stream>>>(states, csum);

    // 7) Y diag + off -> zx[:, DINNER:2*DINNER] (bf16)
    y_kernel<<<dim3(BATCH * NCHUNK * NHEADS, 2), blk, 0, stream>>>(xBC, dtb, cum, states, zx);

    // 8) gate + layernorm (in place on y region of zx)
    gate_ln<<<dim3(ROWS), blk, 0, stream>>>(zx, ln_w, ln_b);

    // 9) out_proj GEMM: out = ynorm @ out_proj_w^T + b   (bf16 A -> fp32 out)
    gemm_bt<1, 0><<<dim3(ROWS / 128, DMODEL / 128), blk, 0, stream>>>(
        (const void*)(zx + DINNER), DINPROJ, out_proj_w, DINNER, out_proj_b, (void*)out, DMODEL, ROWS, DMODEL, DINNER);
}

// Round 3
// 1889.520 us; speedup vs baseline: 1.5527x; 1.5527x over previous
//
#include <hip/hip_runtime.h>
#include <math.h>

#define BATCH    2
#define SEQ      4096
#define DMODEL   2048
#define DSTATE   64
#define HEADDIM  128
#define NHEADS   32
#define DINNER   4096
#define CONVDIM  4224
#define DINPROJ  8352
#define NCHUNK   16
#define CHUNKL   256
#define ROWS     (BATCH*SEQ)   // 8192

typedef __attribute__((ext_vector_type(8))) __bf16 bf16x8;
typedef __attribute__((ext_vector_type(4))) float floatx4;
typedef __attribute__((ext_vector_type(8))) unsigned short ushort8;

__device__ __forceinline__ unsigned short f2bf(float f) {
    union { float f; unsigned int u; } v; v.f = f;
    unsigned int u = v.u;
    unsigned int r = (u + 0x7FFFu + ((u >> 16) & 1u)) >> 16;
    return (unsigned short)r;
}
__device__ __forceinline__ float bf2f(unsigned short s) {
    union { unsigned int u; float f; } v; v.u = ((unsigned int)s) << 16;
    return v.f;
}

__device__ __forceinline__ void gload_lds16(const unsigned short* g, unsigned short* lds) {
    __builtin_amdgcn_global_load_lds(
        (const __attribute__((address_space(1))) unsigned int*)g,
        (__attribute__((address_space(3))) unsigned int*)lds,
        16, 0, 0);
}

// ---------------- fp32 -> bf16 convert (8 elems/thread, 16B stores) ----------------
__global__ __launch_bounds__(256) void f32_to_bf16_k(
    const float* __restrict__ s, unsigned short* __restrict__ d)
{
    int i = (blockIdx.x * 256 + threadIdx.x) * 8;
    float4 a = *reinterpret_cast<const float4*>(s + i);
    float4 b = *reinterpret_cast<const float4*>(s + i + 4);
    ushort8 o;
    o[0] = f2bf(a.x); o[1] = f2bf(a.y); o[2] = f2bf(a.z); o[3] = f2bf(a.w);
    o[4] = f2bf(b.x); o[5] = f2bf(b.y); o[6] = f2bf(b.z); o[7] = f2bf(b.w);
    *reinterpret_cast<ushort8*>(d + i) = o;
}

// ---------------- GEMM: C[M,N] = A[M,K] * Bt[N,K]^T + bias[N] ----------------
// bf16 A and Bt in global; async global_load_lds staging (16B/lane);
// 128x128 block tile, 4 waves (2x2), each wave 64x64 (4x4 16x16x32 MFMA tiles)
template<int OUT_BF16>
__global__ __launch_bounds__(256) void gemm_bb(
    const unsigned short* __restrict__ A, int lda,
    const unsigned short* __restrict__ Bt, int ldb,
    const float* __restrict__ bias,
    void* __restrict__ Cp, int ldc,
    int M, int N, int K)
{
    __shared__ __align__(16) unsigned short As[128 * 32];
    __shared__ __align__(16) unsigned short Bs[128 * 32];
    const int tid  = threadIdx.x;
    const int bm   = blockIdx.x;
    const int bn   = blockIdx.y;
    const int wave = tid >> 6;
    const int lane = tid & 63;
    const int wm   = (wave >> 1) * 64;
    const int wn   = (wave & 1) * 64;
    const int q    = lane >> 4;
    const int lm   = lane & 15;

    floatx4 acc[4][4] = {};

    const int arow0 = bm * 128;
    const int brow0 = bn * 128;

    // staging geometry: thread t covers row = i*64 + t/4, col8 = (t%4)*8 (16B)
    const int srow = tid >> 2;            // 0..63
    const int scol = (tid & 3) * 8;       // 0,8,16,24
    // wave-uniform LDS bases (bytes -> halfword index): i*4096B + wave*1024B
    unsigned short* AsBase0 = &As[wave * 512];
    unsigned short* AsBase1 = &As[2048 + wave * 512];
    unsigned short* BsBase0 = &Bs[wave * 512];
    unsigned short* BsBase1 = &Bs[2048 + wave * 512];

    const int ar0 = arow0 + srow;
    const int ar1 = arow0 + 64 + srow;
    int br0 = brow0 + srow;       if (br0 >= N) br0 = N - 1;
    int br1 = brow0 + 64 + srow;  if (br1 >= N) br1 = N - 1;

    for (int k0 = 0; k0 < K; k0 += 32) {
        __syncthreads();
        gload_lds16(A  + (size_t)ar0 * lda + k0 + scol, AsBase0);
        gload_lds16(A  + (size_t)ar1 * lda + k0 + scol, AsBase1);
        gload_lds16(Bt + (size_t)br0 * ldb + k0 + scol, BsBase0);
        gload_lds16(Bt + (size_t)br1 * ldb + k0 + scol, BsBase1);
        __syncthreads();

        bf16x8 af[4], bfv[4];
        #pragma unroll
        for (int mt = 0; mt < 4; ++mt)
            af[mt] = *reinterpret_cast<const bf16x8*>(&As[(wm + mt * 16 + lm) * 32 + q * 8]);
        #pragma unroll
        for (int nt = 0; nt < 4; ++nt)
            bfv[nt] = *reinterpret_cast<const bf16x8*>(&Bs[(wn + nt * 16 + lm) * 32 + q * 8]);
        #pragma unroll
        for (int mt = 0; mt < 4; ++mt)
            #pragma unroll
            for (int nt = 0; nt < 4; ++nt)
                acc[mt][nt] = __builtin_amdgcn_mfma_f32_16x16x32_bf16(af[mt], bfv[nt], acc[mt][nt], 0, 0, 0);
    }

    #pragma unroll
    for (int mt = 0; mt < 4; ++mt) {
        #pragma unroll
        for (int nt = 0; nt < 4; ++nt) {
            int col = brow0 + wn + nt * 16 + lm;
            if (col < N) {
                float bv = bias[col];
                #pragma unroll
                for (int r = 0; r < 4; ++r) {
                    int row = arow0 + wm + mt * 16 + q * 4 + r;
                    float v = acc[mt][nt][r] + bv;
                    if (OUT_BF16)
                        ((unsigned short*)Cp)[(size_t)row * ldc + col] = f2bf(v);
                    else
                        ((float*)Cp)[(size_t)row * ldc + col] = v;
                }
            }
        }
    }
}

// ---------------- causal depthwise conv (w=4) + bias + SiLU ----------------
__global__ __launch_bounds__(256) void conv_silu(
    const unsigned short* __restrict__ zx, const float* __restrict__ conv_w,
    const float* __restrict__ conv_b, unsigned short* __restrict__ xBC)
{
    int idx = blockIdx.x * 256 + threadIdx.x;      // over ROWS*CONVDIM
    int ch  = idx % CONVDIM;
    int l   = (idx / CONVDIM) % SEQ;
    int b   = idx / (CONVDIM * SEQ);
    const unsigned short* base = zx + (size_t)(b * SEQ) * DINPROJ + DINNER + ch;
    float s = conv_b[ch];
    #pragma unroll
    for (int j = 0; j < 4; ++j) {
        int lj = l - 3 + j;
        if (lj >= 0) s += conv_w[ch * 4 + j] * bf2f(base[(size_t)lj * DINPROJ]);
    }
    float sig = 1.f / (1.f + expf(-s));
    xBC[idx] = f2bf(s * sig);
}

// -------- fused: dt=softplus(raw+bias), adt=-exp(A_log)*dt, per-chunk cumsum --------
__global__ __launch_bounds__(256) void dtcum_kernel(
    const unsigned short* __restrict__ zx, const float* __restrict__ dt_bias,
    const float* __restrict__ A_log, float* __restrict__ dtb,
    float* __restrict__ cum, float* __restrict__ csum)
{
    int id = blockIdx.x;                 // (b*16+c)*32+h
    int h  = id & 31;
    int c  = (id >> 5) & 15;
    int b  = id >> 9;
    int t  = threadIdx.x;
    int row = b * SEQ + c * CHUNKL + t;
    float v = bf2f(zx[(size_t)row * DINPROJ + DINNER + CONVDIM + h]) + dt_bias[h];
    float dtv = (v > 20.f) ? v : log1pf(expf(v));
    dtb[row * NHEADS + h] = dtv;
    float adt = -expf(A_log[h]) * dtv;
    __shared__ float s[256];
    s[t] = adt;
    __syncthreads();
    for (int off = 1; off < 256; off <<= 1) {
        float x = (t >= off) ? s[t - off] : 0.f;
        __syncthreads();
        s[t] += x;
        __syncthreads();
    }
    cum[id * 256 + t] = s[t];
    if (t == 255) csum[id] = s[255];
}

// ---------------- chunk states: st[p,n] = sum_l B[l,n]*exp(cumlast-cum[l])*Xd[l,p] ----------------
__global__ __launch_bounds__(256) void states_kernel(
    const unsigned short* __restrict__ xBC, const float* __restrict__ dtb,
    const float* __restrict__ cum, float* __restrict__ states)
{
    int id = blockIdx.x;                 // (b*16+c)*32+h
    int h  = id & 31;
    int c  = (id >> 5) & 15;
    int b  = id >> 9;
    int t  = threadIdx.x;
    int p  = t >> 1;
    int nh = (t & 1) * 32;
    __shared__ float Btile[32][64];
    __shared__ float Xdt[32][128];
    __shared__ float wl[32];
    float st[32] = {};
    int cumbase = id * 256;
    float cumlast = cum[cumbase + 255];
    for (int lt = 0; lt < 256; lt += 32) {
        __syncthreads();
        #pragma unroll
        for (int i = 0; i < 8; ++i) {
            int idx2 = t + i * 256;          // 2048 = 32*64
            int s2 = idx2 >> 6, n2 = idx2 & 63;
            int row = b * SEQ + c * CHUNKL + lt + s2;
            Btile[s2][n2] = bf2f(xBC[(size_t)row * CONVDIM + DINNER + n2]);
        }
        #pragma unroll
        for (int i = 0; i < 16; ++i) {
            int idx2 = t + i * 256;          // 4096 = 32*128
            int s2 = idx2 >> 7, p2 = idx2 & 127;
            int row = b * SEQ + c * CHUNKL + lt + s2;
            Xdt[s2][p2] = bf2f(xBC[(size_t)row * CONVDIM + h * HEADDIM + p2]) * dtb[row * NHEADS + h];
        }
        if (t < 32) wl[t] = expf(cumlast - cum[cumbase + lt + t]);
        __syncthreads();
        for (int s2 = 0; s2 < 32; ++s2) {
            float f = wl[s2] * Xdt[s2][p];
            #pragma unroll
            for (int n2 = 0; n2 < 32; ++n2) st[n2] += f * Btile[s2][nh + n2];
        }
    }
    size_t obase = (size_t)id * 8192 + (size_t)p * 64 + nh;
    #pragma unroll
    for (int n2 = 0; n2 < 32; ++n2) states[obase + n2] = st[n2];
}

// ---------------- inter-chunk recurrence (in-place) ----------------
__global__ __launch_bounds__(256) void inter_kernel(
    float* __restrict__ states, const float* __restrict__ csum)
{
    int idx = blockIdx.x * 256 + threadIdx.x;      // BATCH*NHEADS*8192
    int pn  = idx & 8191;
    int h   = (idx >> 13) & 31;
    int b   = idx >> 18;
    float S = 0.f;
    for (int c = 0; c < 16; ++c) {
        int id = (b * 16 + c) * 32 + h;
        size_t off = (size_t)id * 8192 + pn;
        float st = states[off];
        states[off] = S;
        S = S * expf(csum[id]) + st;
    }
}

// ---------------- Y = Y_diag + Y_off; writes bf16 into zx[:, DINNER + ...] ----------------
__global__ __launch_bounds__(256) void y_kernel(
    const unsigned short* __restrict__ xBC, const float* __restrict__ dtb,
    const float* __restrict__ cum, const float* __restrict__ inter,
    unsigned short* __restrict__ zx)
{
    int id = blockIdx.x;                 // (b*16+c)*32+h
    int ph = blockIdx.y;                 // p-half
    int h  = id & 31;
    int c  = (id >> 5) & 15;
    int b  = id >> 9;
    int t  = threadIdx.x;                // = l within chunk
    __shared__ float cums[256];
    __shared__ float interS[64][64];
    __shared__ float Btile[32][64];
    __shared__ float Xdt[32][64];

    int cumbase = id * 256;
    cums[t] = cum[cumbase + t];

    int row_l = b * SEQ + c * CHUNKL + t;
    float creg[64];
    const unsigned short* crow = &xBC[(size_t)row_l * CONVDIM + DINNER + DSTATE];
    #pragma unroll
    for (int n = 0; n < 64; ++n) creg[n] = bf2f(crow[n]);

    size_t ibase = (size_t)id * 8192 + (size_t)ph * 64 * 64;
    #pragma unroll
    for (int i = 0; i < 16; ++i) {
        int idx2 = t + i * 256;          // 4096 = 64*64
        interS[idx2 >> 6][idx2 & 63] = inter[ibase + idx2];
    }
    __syncthreads();

    float mycum = cums[t];
    float efac  = expf(mycum);
    float yacc[64];
    #pragma unroll
    for (int p = 0; p < 64; ++p) yacc[p] = 0.f;

    // Y_off
    for (int n = 0; n < 64; ++n) {
        float cf = creg[n] * efac;
        #pragma unroll
        for (int p = 0; p < 64; ++p) yacc[p] += cf * interS[p][n];
    }

    // Y_diag
    for (int st0 = 0; st0 < 256; st0 += 32) {
        __syncthreads();
        #pragma unroll
        for (int i = 0; i < 8; ++i) {
            int idx2 = t + i * 256;      // 2048 = 32*64
            int s2 = idx2 >> 6, n2 = idx2 & 63;
            int row_s = b * SEQ + c * CHUNKL + st0 + s2;
            Btile[s2][n2] = bf2f(xBC[(size_t)row_s * CONVDIM + DINNER + n2]);
            Xdt[s2][n2]   = bf2f(xBC[(size_t)row_s * CONVDIM + h * HEADDIM + ph * 64 + n2])
                            * dtb[row_s * NHEADS + h];
        }
        __syncthreads();
        if (t >= st0) {
            int lim = t - st0 + 1;
            int smax = (lim < 32) ? lim : 32;
            for (int s2 = 0; s2 < smax; ++s2) {
                float dot = 0.f;
                #pragma unroll
                for (int n = 0; n < 64; ++n) dot += creg[n] * Btile[s2][n];
                float sc = dot * expf(mycum - cums[st0 + s2]);
                #pragma unroll
                for (int p = 0; p < 64; ++p) yacc[p] += sc * Xdt[s2][p];
            }
        }
    }

    size_t ybase = (size_t)row_l * DINPROJ + DINNER + h * HEADDIM + ph * 64;
    #pragma unroll
    for (int p = 0; p < 64; ++p) zx[ybase + p] = f2bf(yacc[p]);
}

// ---------------- y * silu(z), LayerNorm (in place over y region of zx, bf16) ----------------
__global__ __launch_bounds__(256) void gate_ln(
    unsigned short* __restrict__ zx, const float* __restrict__ ln_w, const float* __restrict__ ln_b)
{
    int row = blockIdx.x;
    int t   = threadIdx.x;
    size_t base = (size_t)row * DINPROJ;
    float g[16];
    float sum = 0.f, sumsq = 0.f;
    #pragma unroll
    for (int j = 0; j < 16; ++j) {
        int i = t + j * 256;
        float z = bf2f(zx[base + i]);
        float y = bf2f(zx[base + DINNER + i]);
        float sig = 1.f / (1.f + expf(-z));
        float v = y * z * sig;
        g[j] = v;
        sum += v; sumsq += v * v;
    }
    __shared__ float rs[256], rq[256];
    rs[t] = sum; rq[t] = sumsq;
    __syncthreads();
    for (int off = 128; off > 0; off >>= 1) {
        if (t < off) { rs[t] += rs[t + off]; rq[t] += rq[t + off]; }
        __syncthreads();
    }
    float mu   = rs[0] * (1.f / DINNER);
    float var  = rq[0] * (1.f / DINNER) - mu * mu;
    float rstd = rsqrtf(var + 1e-5f);
    #pragma unroll
    for (int j = 0; j < 16; ++j) {
        int i = t + j * 256;
        zx[base + DINNER + i] = f2bf((g[j] - mu) * rstd * ln_w[i] + ln_b[i]);
    }
}

extern "C" void kernel_launch(void* const* d_in, const int* in_sizes, int n_in,
                              void* d_out, int out_size, void* d_ws, size_t ws_size,
                              hipStream_t stream)
{
    const float* u          = (const float*)d_in[0];
    const float* in_proj_w  = (const float*)d_in[1];
    const float* in_proj_b  = (const float*)d_in[2];
    const float* conv_w     = (const float*)d_in[3];
    const float* conv_b     = (const float*)d_in[4];
    const float* dt_bias    = (const float*)d_in[5];
    const float* A_log      = (const float*)d_in[6];
    const float* ln_w       = (const float*)d_in[7];
    const float* ln_b       = (const float*)d_in[8];
    const float* out_proj_w = (const float*)d_in[9];
    const float* out_proj_b = (const float*)d_in[10];
    float* out = (float*)d_out;

    // workspace layout (~230.5 MiB):
    unsigned short* zx  = (unsigned short*)d_ws;              // ROWS*DINPROJ bf16
    unsigned short* xBC = zx + (size_t)ROWS * DINPROJ;        // ROWS*CONVDIM bf16
    float* dtb    = (float*)(xBC + (size_t)ROWS * CONVDIM);   // ROWS*NHEADS f32
    float* cum    = dtb + (size_t)ROWS * NHEADS;              // ROWS*NHEADS f32
    float* csum   = cum + (size_t)ROWS * NHEADS;              // 1024 f32
    float* states = csum + 1024;                              // 1024*8192 f32 (33.55 MB)

    // aliased bf16 staging buffers (schedule guarantees no live overlap):
    unsigned short* u_bf  = (unsigned short*)states;          // 33.55 MB == states size
    unsigned short* w1_bf = xBC;                              // dead until conv writes it
    unsigned short* w2_bf = (unsigned short*)states;          // states dead after y_kernel

    dim3 blk(256);

    // 0) fp32 -> bf16 converts for gemm1 operands
    f32_to_bf16_k<<<dim3((ROWS * DMODEL) / 2048), blk, 0, stream>>>(u, u_bf);
    f32_to_bf16_k<<<dim3((DINPROJ * DMODEL) / 2048), blk, 0, stream>>>(in_proj_w, w1_bf);

    // 1) in_proj GEMM: zx = u @ in_proj_w^T + b   (bf16 x bf16 -> bf16)
    gemm_bb<1><<<dim3(ROWS / 128, (DINPROJ + 127) / 128), blk, 0, stream>>>(
        u_bf, DMODEL, w1_bf, DMODEL, in_proj_b, (void*)zx, DINPROJ, ROWS, DINPROJ, DMODEL);

    // 2) conv + silu -> xBC (bf16; overwrites w1_bf region, now dead)
    conv_silu<<<dim3((ROWS * CONVDIM) / 256), blk, 0, stream>>>(zx, conv_w, conv_b, xBC);

    // 3+4) dt / adt / per-chunk cumsum
    dtcum_kernel<<<dim3(BATCH * NCHUNK * NHEADS), blk, 0, stream>>>(zx, dt_bias, A_log, dtb, cum, csum);

    // 5) chunk states (overwrites u_bf region, now dead)
    states_kernel<<<dim3(BATCH * NCHUNK * NHEADS), blk, 0, stream>>>(xBC, dtb, cum, states);

    // 6) inter-chunk recurrence (in place)
    inter_kernel<<<dim3((BATCH * NHEADS * 8192) / 256), blk, 0, stream>>>(states, csum);

    // 7) Y diag + off -> zx[:, DINNER:2*DINNER] (bf16)
    y_kernel<<<dim3(BATCH * NCHUNK * NHEADS, 2), blk, 0, stream>>>(xBC, dtb, cum, states, zx);

    // 8) gate + layernorm (in place on y region of zx)
    gate_ln<<<dim3(ROWS), blk, 0, stream>>>(zx, ln_w, ln_b);

    // 9) out_proj: convert weight, then GEMM (bf16 x bf16 -> fp32 out)
    f32_to_bf16_k<<<dim3((DMODEL * DINNER) / 2048), blk, 0, stream>>>(out_proj_w, w2_bf);
    gemm_bb<0><<<dim3(ROWS / 128, DMODEL / 128), blk, 0, stream>>>(
        (const unsigned short*)(zx + DINNER), DINPROJ, w2_bf, DINNER, out_proj_b, (void*)out,
        DMODEL, ROWS, DMODEL, DINNER);
}

// Round 4
// 1223.880 us; speedup vs baseline: 2.3971x; 1.5439x over previous
//
#include <hip/hip_runtime.h>
#include <math.h>

#define BATCH    2
#define SEQ      4096
#define DMODEL   2048
#define DSTATE   64
#define HEADDIM  128
#define NHEADS   32
#define DINNER   4096
#define CONVDIM  4224
#define DINPROJ  8352
#define NCHUNK   16
#define CHUNKL   256
#define ROWS     (BATCH*SEQ)   // 8192

typedef __attribute__((ext_vector_type(8))) __bf16 bf16x8;
typedef __attribute__((ext_vector_type(4))) float floatx4;
typedef __attribute__((ext_vector_type(8))) unsigned short ushort8;

__device__ __forceinline__ unsigned short f2bf(float f) {
    union { float f; unsigned int u; } v; v.f = f;
    unsigned int u = v.u;
    unsigned int r = (u + 0x7FFFu + ((u >> 16) & 1u)) >> 16;
    return (unsigned short)r;
}
__device__ __forceinline__ float bf2f(unsigned short s) {
    union { unsigned int u; float f; } v; v.u = ((unsigned int)s) << 16;
    return v.f;
}

__device__ __forceinline__ void gload_lds16(const unsigned short* g, unsigned short* lds) {
    __builtin_amdgcn_global_load_lds(
        (const __attribute__((address_space(1))) unsigned int*)g,
        (__attribute__((address_space(3))) unsigned int*)lds,
        16, 0, 0);
}

// ---------------- fp32 -> bf16 convert ----------------
__global__ __launch_bounds__(256) void f32_to_bf16_k(
    const float* __restrict__ s, unsigned short* __restrict__ d)
{
    int i = (blockIdx.x * 256 + threadIdx.x) * 8;
    float4 a = *reinterpret_cast<const float4*>(s + i);
    float4 b = *reinterpret_cast<const float4*>(s + i + 4);
    ushort8 o;
    o[0] = f2bf(a.x); o[1] = f2bf(a.y); o[2] = f2bf(a.z); o[3] = f2bf(a.w);
    o[4] = f2bf(b.x); o[5] = f2bf(b.y); o[6] = f2bf(b.z); o[7] = f2bf(b.w);
    *reinterpret_cast<ushort8*>(d + i) = o;
}

// ---------------- GEMM: C[M,N] = A[M,K] * Bt[N,K]^T + bias[N] ----------------
template<int OUT_BF16>
__global__ __launch_bounds__(256) void gemm_bb(
    const unsigned short* __restrict__ A, int lda,
    const unsigned short* __restrict__ Bt, int ldb,
    const float* __restrict__ bias,
    void* __restrict__ Cp, int ldc,
    int M, int N, int K)
{
    __shared__ __align__(16) unsigned short As[128 * 32];
    __shared__ __align__(16) unsigned short Bs[128 * 32];
    const int tid  = threadIdx.x;
    const int bm   = blockIdx.x;
    const int bn   = blockIdx.y;
    const int wave = tid >> 6;
    const int lane = tid & 63;
    const int wm   = (wave >> 1) * 64;
    const int wn   = (wave & 1) * 64;
    const int q    = lane >> 4;
    const int lm   = lane & 15;

    floatx4 acc[4][4] = {};

    const int arow0 = bm * 128;
    const int brow0 = bn * 128;

    const int srow = tid >> 2;
    const int scol = (tid & 3) * 8;
    unsigned short* AsBase0 = &As[wave * 512];
    unsigned short* AsBase1 = &As[2048 + wave * 512];
    unsigned short* BsBase0 = &Bs[wave * 512];
    unsigned short* BsBase1 = &Bs[2048 + wave * 512];

    const int ar0 = arow0 + srow;
    const int ar1 = arow0 + 64 + srow;
    int br0 = brow0 + srow;       if (br0 >= N) br0 = N - 1;
    int br1 = brow0 + 64 + srow;  if (br1 >= N) br1 = N - 1;

    for (int k0 = 0; k0 < K; k0 += 32) {
        __syncthreads();
        gload_lds16(A  + (size_t)ar0 * lda + k0 + scol, AsBase0);
        gload_lds16(A  + (size_t)ar1 * lda + k0 + scol, AsBase1);
        gload_lds16(Bt + (size_t)br0 * ldb + k0 + scol, BsBase0);
        gload_lds16(Bt + (size_t)br1 * ldb + k0 + scol, BsBase1);
        __syncthreads();

        bf16x8 af[4], bfv[4];
        #pragma unroll
        for (int mt = 0; mt < 4; ++mt)
            af[mt] = *reinterpret_cast<const bf16x8*>(&As[(wm + mt * 16 + lm) * 32 + q * 8]);
        #pragma unroll
        for (int nt = 0; nt < 4; ++nt)
            bfv[nt] = *reinterpret_cast<const bf16x8*>(&Bs[(wn + nt * 16 + lm) * 32 + q * 8]);
        #pragma unroll
        for (int mt = 0; mt < 4; ++mt)
            #pragma unroll
            for (int nt = 0; nt < 4; ++nt)
                acc[mt][nt] = __builtin_amdgcn_mfma_f32_16x16x32_bf16(af[mt], bfv[nt], acc[mt][nt], 0, 0, 0);
    }

    #pragma unroll
    for (int mt = 0; mt < 4; ++mt) {
        #pragma unroll
        for (int nt = 0; nt < 4; ++nt) {
            int col = brow0 + wn + nt * 16 + lm;
            if (col < N) {
                float bv = bias[col];
                #pragma unroll
                for (int r = 0; r < 4; ++r) {
                    int row = arow0 + wm + mt * 16 + q * 4 + r;
                    float v = acc[mt][nt][r] + bv;
                    if (OUT_BF16)
                        ((unsigned short*)Cp)[(size_t)row * ldc + col] = f2bf(v);
                    else
                        ((float*)Cp)[(size_t)row * ldc + col] = v;
                }
            }
        }
    }
}

// ---------------- causal depthwise conv (w=4) + bias + SiLU ----------------
__global__ __launch_bounds__(256) void conv_silu(
    const unsigned short* __restrict__ zx, const float* __restrict__ conv_w,
    const float* __restrict__ conv_b, unsigned short* __restrict__ xBC)
{
    int idx = blockIdx.x * 256 + threadIdx.x;
    int ch  = idx % CONVDIM;
    int l   = (idx / CONVDIM) % SEQ;
    int b   = idx / (CONVDIM * SEQ);
    const unsigned short* base = zx + (size_t)(b * SEQ) * DINPROJ + DINNER + ch;
    float s = conv_b[ch];
    #pragma unroll
    for (int j = 0; j < 4; ++j) {
        int lj = l - 3 + j;
        if (lj >= 0) s += conv_w[ch * 4 + j] * bf2f(base[(size_t)lj * DINPROJ]);
    }
    float sig = 1.f / (1.f + __expf(-s));
    xBC[idx] = f2bf(s * sig);
}

// -------- fused: dt=softplus(raw+bias), adt=-exp(A_log)*dt, per-chunk cumsum --------
__global__ __launch_bounds__(256) void dtcum_kernel(
    const unsigned short* __restrict__ zx, const float* __restrict__ dt_bias,
    const float* __restrict__ A_log, float* __restrict__ dtb,
    float* __restrict__ cum, float* __restrict__ csum)
{
    int id = blockIdx.x;
    int h  = id & 31;
    int c  = (id >> 5) & 15;
    int b  = id >> 9;
    int t  = threadIdx.x;
    int row = b * SEQ + c * CHUNKL + t;
    float v = bf2f(zx[(size_t)row * DINPROJ + DINNER + CONVDIM + h]) + dt_bias[h];
    float dtv = (v > 20.f) ? v : log1pf(__expf(v));
    dtb[row * NHEADS + h] = dtv;
    float adt = -__expf(A_log[h]) * dtv;
    __shared__ float s[256];
    s[t] = adt;
    __syncthreads();
    for (int off = 1; off < 256; off <<= 1) {
        float x = (t >= off) ? s[t - off] : 0.f;
        __syncthreads();
        s[t] += x;
        __syncthreads();
    }
    cum[id * 256 + t] = s[t];
    if (t == 255) csum[id] = s[255];
}

// ---------------- scores: S_raw[bc][l][s] = C[l].B[s] (head-independent) ----------------
__global__ __launch_bounds__(256) void score_kernel(
    const unsigned short* __restrict__ xBC, unsigned short* __restrict__ S_raw)
{
    int bc = blockIdx.x;        // 0..63 = b*16+c
    int sq = blockIdx.y;        // 0..3 s-quadrant
    int tid = threadIdx.x;
    int wave = tid >> 6, lane = tid & 63, q = lane >> 4, lm = lane & 15;
    __shared__ __align__(16) unsigned short Ct[256 * 72];
    __shared__ __align__(16) unsigned short Btl[64 * 72];

    #pragma unroll
    for (int i = 0; i < 8; ++i) {
        int idx = tid + 256 * i;
        int r = idx >> 3, ch = idx & 7;
        ushort8 v = *reinterpret_cast<const ushort8*>(
            &xBC[(size_t)(bc * 256 + r) * CONVDIM + DINNER + DSTATE + ch * 8]);
        *reinterpret_cast<ushort8*>(&Ct[r * 72 + ch * 8]) = v;
    }
    #pragma unroll
    for (int i = 0; i < 2; ++i) {
        int idx = tid + 256 * i;
        int r = idx >> 3, ch = idx & 7;
        ushort8 v = *reinterpret_cast<const ushort8*>(
            &xBC[(size_t)(bc * 256 + sq * 64 + r) * CONVDIM + DINNER + ch * 8]);
        *reinterpret_cast<ushort8*>(&Btl[r * 72 + ch * 8]) = v;
    }
    __syncthreads();

    floatx4 acc[4][4] = {};
    #pragma unroll
    for (int ks = 0; ks < 2; ++ks) {
        bf16x8 af[4], bfv[4];
        #pragma unroll
        for (int mt = 0; mt < 4; ++mt)
            af[mt] = *reinterpret_cast<const bf16x8*>(&Ct[(wave * 64 + mt * 16 + lm) * 72 + ks * 32 + q * 8]);
        #pragma unroll
        for (int nt = 0; nt < 4; ++nt)
            bfv[nt] = *reinterpret_cast<const bf16x8*>(&Btl[(nt * 16 + lm) * 72 + ks * 32 + q * 8]);
        #pragma unroll
        for (int mt = 0; mt < 4; ++mt)
            #pragma unroll
            for (int nt = 0; nt < 4; ++nt)
                acc[mt][nt] = __builtin_amdgcn_mfma_f32_16x16x32_bf16(af[mt], bfv[nt], acc[mt][nt], 0, 0, 0);
    }

    #pragma unroll
    for (int mt = 0; mt < 4; ++mt)
        #pragma unroll
        for (int nt = 0; nt < 4; ++nt) {
            int l = wave * 64 + mt * 16 + q * 4;
            int s = sq * 64 + nt * 16 + lm;
            #pragma unroll
            for (int r = 0; r < 4; ++r)
                S_raw[(size_t)(bc * 256 + l + r) * 256 + s] = f2bf(acc[mt][nt][r]);
        }
}

// ---------------- chunk states ----------------
__global__ __launch_bounds__(256) void states_kernel(
    const unsigned short* __restrict__ xBC, const float* __restrict__ dtb,
    const float* __restrict__ cum, float* __restrict__ states)
{
    int id = blockIdx.x;
    int h  = id & 31;
    int c  = (id >> 5) & 15;
    int b  = id >> 9;
    int t  = threadIdx.x;
    int p  = t >> 1;
    int nh = (t & 1) * 32;
    __shared__ float Btile[32][64];
    __shared__ float Xdt[32][128];
    __shared__ float wl[32];
    float st[32] = {};
    int cumbase = id * 256;
    float cumlast = cum[cumbase + 255];
    for (int lt = 0; lt < 256; lt += 32) {
        __syncthreads();
        #pragma unroll
        for (int i = 0; i < 8; ++i) {
            int idx2 = t + i * 256;
            int s2 = idx2 >> 6, n2 = idx2 & 63;
            int row = b * SEQ + c * CHUNKL + lt + s2;
            Btile[s2][n2] = bf2f(xBC[(size_t)row * CONVDIM + DINNER + n2]);
        }
        #pragma unroll
        for (int i = 0; i < 16; ++i) {
            int idx2 = t + i * 256;
            int s2 = idx2 >> 7, p2 = idx2 & 127;
            int row = b * SEQ + c * CHUNKL + lt + s2;
            Xdt[s2][p2] = bf2f(xBC[(size_t)row * CONVDIM + h * HEADDIM + p2]) * dtb[row * NHEADS + h];
        }
        if (t < 32) wl[t] = __expf(cumlast - cum[cumbase + lt + t]);
        __syncthreads();
        for (int s2 = 0; s2 < 32; ++s2) {
            float f = wl[s2] * Xdt[s2][p];
            #pragma unroll
            for (int n2 = 0; n2 < 32; ++n2) st[n2] += f * Btile[s2][nh + n2];
        }
    }
    size_t obase = (size_t)id * 8192 + (size_t)p * 64 + nh;
    #pragma unroll
    for (int n2 = 0; n2 < 32; ++n2) states[obase + n2] = st[n2];
}

// ---------------- inter-chunk recurrence (in-place) ----------------
__global__ __launch_bounds__(256) void inter_kernel(
    float* __restrict__ states, const float* __restrict__ csum)
{
    int idx = blockIdx.x * 256 + threadIdx.x;
    int pn  = idx & 8191;
    int h   = (idx >> 13) & 31;
    int b   = idx >> 18;
    float S = 0.f;
    for (int c = 0; c < 16; ++c) {
        int id = (b * 16 + c) * 32 + h;
        size_t off = (size_t)id * 8192 + pn;
        float st = states[off];
        states[off] = S;
        S = S * __expf(csum[id]) + st;
    }
}

// ---------------- Y via MFMA: Y = P.XdtT + (C*efac).interS^T ----------------
__global__ __launch_bounds__(256) void y_mfma(
    const unsigned short* __restrict__ xBC,
    const unsigned short* __restrict__ S_raw,
    const float* __restrict__ dtb,
    const float* __restrict__ cum,
    const float* __restrict__ inter,
    unsigned short* __restrict__ zx)
{
    int id = blockIdx.x;               // (b*16+c)*32 + h
    int h  = id & 31;
    int bc = id >> 5;
    int tid = threadIdx.x, wave = tid >> 6, lane = tid & 63, q = lane >> 4, lm = lane & 15;
    int wl = wave >> 1, wp = wave & 1;

    __shared__ float cums[256];
    __shared__ float dts[256];
    __shared__ __align__(16) unsigned short XdtT[128 * 72];   // [p][64s + 8 pad]
    __shared__ __align__(16) unsigned short PT[128 * 72];     // P[128][72] or T1[64][136]

    cums[tid] = cum[id * 256 + tid];
    dts[tid]  = dtb[(size_t)(bc * 256 + tid) * NHEADS + h];
    __syncthreads();

    for (int lh = 0; lh < 2; ++lh) {
        floatx4 acc[4][4] = {};
        const int l0w = lh * 128 + wl * 64;
        const int nst = 2 * lh + 2;

        for (int st = 0; st < nst; ++st) {
            const int s0 = st * 64;
            // --- T1 stage: Xdt natural [64 s][136] (into PT) ---
            __syncthreads();
            #pragma unroll
            for (int i = 0; i < 4; ++i) {
                int idx = tid + 256 * i;
                int sr = idx >> 4, ch = idx & 15;
                int srow = bc * 256 + s0 + sr;
                ushort8 v = *reinterpret_cast<const ushort8*>(
                    &xBC[(size_t)srow * CONVDIM + h * HEADDIM + ch * 8]);
                float dt = dts[s0 + sr];
                ushort8 o;
                #pragma unroll
                for (int j = 0; j < 8; ++j) o[j] = f2bf(bf2f(v[j]) * dt);
                *reinterpret_cast<ushort8*>(&PT[sr * 136 + ch * 8]) = o;
            }
            __syncthreads();
            // --- transpose T1 -> XdtT[p][72] ---
            {
                int p = tid & 127, sb = (tid >> 7) * 8;
                #pragma unroll
                for (int k2 = 0; k2 < 4; ++k2) {
                    int sbase = sb + k2 * 16;
                    ushort8 o;
                    #pragma unroll
                    for (int j = 0; j < 8; ++j) o[j] = PT[(sbase + j) * 136 + p];
                    *reinterpret_cast<ushort8*>(&XdtT[p * 72 + sbase]) = o;
                }
            }
            __syncthreads();
            // --- P stage: rows r in [r0,128) of this half (decay+mask, bf16) ---
            const int r0 = (s0 > lh * 128) ? 64 : 0;
            const int iters = (128 - r0) >> 5;
            for (int i = 0; i < iters; ++i) {
                int idx = tid + 256 * i;
                int r = r0 + (idx >> 3), ch = idx & 7;
                int l = lh * 128 + r;
                float cl = cums[l];
                ushort8 v = *reinterpret_cast<const ushort8*>(
                    &S_raw[(size_t)(bc * 256 + l) * 256 + s0 + ch * 8]);
                ushort8 o;
                #pragma unroll
                for (int j = 0; j < 8; ++j) {
                    int s = s0 + ch * 8 + j;
                    float val = (s <= l) ? bf2f(v[j]) * __expf(cl - cums[s]) : 0.f;
                    o[j] = f2bf(val);
                }
                *reinterpret_cast<ushort8*>(&PT[r * 72 + ch * 8]) = o;
            }
            __syncthreads();
            // --- MFMA (waves with l >= s participate) ---
            if (s0 <= l0w) {
                #pragma unroll
                for (int ks = 0; ks < 2; ++ks) {
                    bf16x8 af[4], bfv[4];
                    #pragma unroll
                    for (int mt = 0; mt < 4; ++mt)
                        af[mt] = *reinterpret_cast<const bf16x8*>(
                            &PT[(wl * 64 + mt * 16 + lm) * 72 + ks * 32 + q * 8]);
                    #pragma unroll
                    for (int nt = 0; nt < 4; ++nt)
                        bfv[nt] = *reinterpret_cast<const bf16x8*>(
                            &XdtT[(wp * 64 + nt * 16 + lm) * 72 + ks * 32 + q * 8]);
                    #pragma unroll
                    for (int mt = 0; mt < 4; ++mt)
                        #pragma unroll
                        for (int nt = 0; nt < 4; ++nt)
                            acc[mt][nt] = __builtin_amdgcn_mfma_f32_16x16x32_bf16(af[mt], bfv[nt], acc[mt][nt], 0, 0, 0);
                }
            }
        }

        // --- virtual tile: Y_off = (C*efac) . interS^T ---
        __syncthreads();
        {
            int p = tid >> 1, n0 = (tid & 1) * 32;
            const float* sp = &inter[(size_t)id * 8192 + p * 64 + n0];
            #pragma unroll
            for (int k2 = 0; k2 < 4; ++k2) {
                float4 a = *reinterpret_cast<const float4*>(sp + k2 * 8);
                float4 b2 = *reinterpret_cast<const float4*>(sp + k2 * 8 + 4);
                ushort8 o;
                o[0] = f2bf(a.x); o[1] = f2bf(a.y); o[2] = f2bf(a.z); o[3] = f2bf(a.w);
                o[4] = f2bf(b2.x); o[5] = f2bf(b2.y); o[6] = f2bf(b2.z); o[7] = f2bf(b2.w);
                *reinterpret_cast<ushort8*>(&XdtT[p * 72 + n0 + k2 * 8]) = o;
            }
            int r = tid >> 1;
            int l = lh * 128 + r;
            float ef = __expf(cums[l]);
            const unsigned short* cp = &xBC[(size_t)(bc * 256 + l) * CONVDIM + DINNER + DSTATE + n0];
            #pragma unroll
            for (int k2 = 0; k2 < 4; ++k2) {
                ushort8 v = *reinterpret_cast<const ushort8*>(cp + k2 * 8);
                ushort8 o;
                #pragma unroll
                for (int j = 0; j < 8; ++j) o[j] = f2bf(bf2f(v[j]) * ef);
                *reinterpret_cast<ushort8*>(&PT[r * 72 + n0 + k2 * 8]) = o;
            }
        }
        __syncthreads();
        #pragma unroll
        for (int ks = 0; ks < 2; ++ks) {
            bf16x8 af[4], bfv[4];
            #pragma unroll
            for (int mt = 0; mt < 4; ++mt)
                af[mt] = *reinterpret_cast<const bf16x8*>(
                    &PT[(wl * 64 + mt * 16 + lm) * 72 + ks * 32 + q * 8]);
            #pragma unroll
            for (int nt = 0; nt < 4; ++nt)
                bfv[nt] = *reinterpret_cast<const bf16x8*>(
                    &XdtT[(wp * 64 + nt * 16 + lm) * 72 + ks * 32 + q * 8]);
            #pragma unroll
            for (int mt = 0; mt < 4; ++mt)
                #pragma unroll
                for (int nt = 0; nt < 4; ++nt)
                    acc[mt][nt] = __builtin_amdgcn_mfma_f32_16x16x32_bf16(af[mt], bfv[nt], acc[mt][nt], 0, 0, 0);
        }

        // --- epilogue: write Y (bf16) into zx y-region ---
        #pragma unroll
        for (int mt = 0; mt < 4; ++mt)
            #pragma unroll
            for (int nt = 0; nt < 4; ++nt) {
                int l = lh * 128 + wl * 64 + mt * 16 + q * 4;
                int pcol = wp * 64 + nt * 16 + lm;
                #pragma unroll
                for (int r = 0; r < 4; ++r)
                    zx[(size_t)(bc * 256 + l + r) * DINPROJ + DINNER + h * HEADDIM + pcol]
                        = f2bf(acc[mt][nt][r]);
            }
    }
}

// ---------------- y * silu(z), LayerNorm ----------------
__global__ __launch_bounds__(256) void gate_ln(
    unsigned short* __restrict__ zx, const float* __restrict__ ln_w, const float* __restrict__ ln_b)
{
    int row = blockIdx.x;
    int t   = threadIdx.x;
    size_t base = (size_t)row * DINPROJ;
    float g[16];
    float sum = 0.f, sumsq = 0.f;
    #pragma unroll
    for (int j = 0; j < 16; ++j) {
        int i = t + j * 256;
        float z = bf2f(zx[base + i]);
        float y = bf2f(zx[base + DINNER + i]);
        float sig = 1.f / (1.f + __expf(-z));
        float v = y * z * sig;
        g[j] = v;
        sum += v; sumsq += v * v;
    }
    __shared__ float rs[256], rq[256];
    rs[t] = sum; rq[t] = sumsq;
    __syncthreads();
    for (int off = 128; off > 0; off >>= 1) {
        if (t < off) { rs[t] += rs[t + off]; rq[t] += rq[t + off]; }
        __syncthreads();
    }
    float mu   = rs[0] * (1.f / DINNER);
    float var  = rq[0] * (1.f / DINNER) - mu * mu;
    float rstd = rsqrtf(var + 1e-5f);
    #pragma unroll
    for (int j = 0; j < 16; ++j) {
        int i = t + j * 256;
        zx[base + DINNER + i] = f2bf((g[j] - mu) * rstd * ln_w[i] + ln_b[i]);
    }
}

extern "C" void kernel_launch(void* const* d_in, const int* in_sizes, int n_in,
                              void* d_out, int out_size, void* d_ws, size_t ws_size,
                              hipStream_t stream)
{
    const float* u          = (const float*)d_in[0];
    const float* in_proj_w  = (const float*)d_in[1];
    const float* in_proj_b  = (const float*)d_in[2];
    const float* conv_w     = (const float*)d_in[3];
    const float* conv_b     = (const float*)d_in[4];
    const float* dt_bias    = (const float*)d_in[5];
    const float* A_log      = (const float*)d_in[6];
    const float* ln_w       = (const float*)d_in[7];
    const float* ln_b       = (const float*)d_in[8];
    const float* out_proj_w = (const float*)d_in[9];
    const float* out_proj_b = (const float*)d_in[10];
    float* out = (float*)d_out;

    // workspace layout (~238.5 MiB)
    unsigned short* zx  = (unsigned short*)d_ws;              // ROWS*DINPROJ bf16
    unsigned short* xBC = zx + (size_t)ROWS * DINPROJ;        // ROWS*CONVDIM bf16
    float* dtb    = (float*)(xBC + (size_t)ROWS * CONVDIM);   // ROWS*NHEADS f32
    float* cum    = dtb + (size_t)ROWS * NHEADS;              // ROWS*NHEADS f32
    float* csum   = cum + (size_t)ROWS * NHEADS;              // 1024 f32
    float* states = csum + 1024;                              // 1024*8192 f32
    unsigned short* S_raw = (unsigned short*)(states + (size_t)1024 * 8192); // 64*256*256 bf16

    // aliases (no live overlap):
    unsigned short* u_bf  = (unsigned short*)states;
    unsigned short* w1_bf = xBC;
    unsigned short* w2_bf = (unsigned short*)states;

    dim3 blk(256);

    f32_to_bf16_k<<<dim3((ROWS * DMODEL) / 2048), blk, 0, stream>>>(u, u_bf);
    f32_to_bf16_k<<<dim3((DINPROJ * DMODEL) / 2048), blk, 0, stream>>>(in_proj_w, w1_bf);

    gemm_bb<1><<<dim3(ROWS / 128, (DINPROJ + 127) / 128), blk, 0, stream>>>(
        u_bf, DMODEL, w1_bf, DMODEL, in_proj_b, (void*)zx, DINPROJ, ROWS, DINPROJ, DMODEL);

    conv_silu<<<dim3((ROWS * CONVDIM) / 256), blk, 0, stream>>>(zx, conv_w, conv_b, xBC);

    dtcum_kernel<<<dim3(BATCH * NCHUNK * NHEADS), blk, 0, stream>>>(zx, dt_bias, A_log, dtb, cum, csum);

    score_kernel<<<dim3(BATCH * NCHUNK, 4), blk, 0, stream>>>(xBC, S_raw);

    states_kernel<<<dim3(BATCH * NCHUNK * NHEADS), blk, 0, stream>>>(xBC, dtb, cum, states);

    inter_kernel<<<dim3((BATCH * NHEADS * 8192) / 256), blk, 0, stream>>>(states, csum);

    y_mfma<<<dim3(BATCH * NCHUNK * NHEADS), blk, 0, stream>>>(xBC, S_raw, dtb, cum, states, zx);

    gate_ln<<<dim3(ROWS), blk, 0, stream>>>(zx, ln_w, ln_b);

    f32_to_bf16_k<<<dim3((DMODEL * DINNER) / 2048), blk, 0, stream>>>(out_proj_w, w2_bf);
    gemm_bb<0><<<dim3(ROWS / 128, DMODEL / 128), blk, 0, stream>>>(
        (const unsigned short*)(zx + DINNER), DINPROJ, w2_bf, DINNER, out_proj_b, (void*)out,
        DMODEL, ROWS, DMODEL, DINNER);
}